// Round 6
// baseline (3575.311 us; speedup 1.0000x reference)
//
#include <hip/hip_runtime.h>
#include <math.h>

// Grid-RNN (WhileOpGridLSTMNet): DEPTH=2, SRC=TRG=32, B=32, H=256
// out[d][i][j][c][b][h], c=0:HX, c=1:HY
#define SRCN 32
#define TRGN 32
#define BN   32
#define HN   256
#define BH   (BN*HN)          // 8192 floats per (cell,channel)
#define CELL (2*BH)           // 16384 floats per cell
#define DSZ  ((size_t)SRCN*TRGN*CELL) // floats per depth

typedef float v8f __attribute__((ext_vector_type(8)));
typedef __attribute__((address_space(4))) const v8f kv8f; // constant AS -> s_load

__host__ __device__ __forceinline__ int ncd(int t) { // cells on diag t (0..62)
    int a = t + 1, b = 63 - t;
    int m = a < b ? a : b;
    return m < 32 ? m : 32;
}

// acc[b] += sum_k srow(b,k) * wcol(k),  K=256.
// srows: WAVE-UNIFORM base of 8 rows (stride HN) -> scalar s_load path.
// wcol:  per-lane weight column base (stride HN between k) -> vector loads.
__device__ __forceinline__ void gemm8(float* acc, const float* srows,
                                      const float* __restrict__ wcol)
{
    for (int k = 0; k < HN; k += 8) {
        float w0 = wcol[(k+0)*HN];
        float w1 = wcol[(k+1)*HN];
        float w2 = wcol[(k+2)*HN];
        float w3 = wcol[(k+3)*HN];
        float w4 = wcol[(k+4)*HN];
        float w5 = wcol[(k+5)*HN];
        float w6 = wcol[(k+6)*HN];
        float w7 = wcol[(k+7)*HN];
#pragma unroll
        for (int b = 0; b < 8; ++b) {
            // inttoptr into constant AS: uniform -> s_load_dwordx8
            kv8f* sp = (kv8f*)(unsigned long long)(srows + b * HN + k);
            v8f sv = *sp;
            acc[b] += sv.s0*w0 + sv.s1*w1 + sv.s2*w2 + sv.s3*w3
                    + sv.s4*w4 + sv.s5*w5 + sv.s6*w6 + sv.s7*w7;
        }
    }
}

// ---------------------------------------------------------------------------
// proj0: xp0[i] = source[i] @ W0 ; yp0[j] = target[j] @ W0   (into ws scratch)
// grid = 64 slices * 4 col-tiles
// ---------------------------------------------------------------------------
__global__ __launch_bounds__(256) void proj0s_kernel(
    const float* __restrict__ src, const float* __restrict__ trg,
    const float* __restrict__ W0,
    float* __restrict__ Xp0, float* __restrict__ Yp0)
{
    const int blk = blockIdx.x >> 2, tile = blockIdx.x & 3;
    const int tid = threadIdx.x;
    const int lane = tid & 63;
    const int bg = __builtin_amdgcn_readfirstlane(tid >> 6);
    const int h = tile * 64 + lane;
    const int r0 = bg * 8;
    const float* xin = (blk < SRCN) ? src + (size_t)blk * BH
                                    : trg + (size_t)(blk - SRCN) * BH;
    float* dst = (blk < SRCN) ? Xp0 + (size_t)blk * BH
                              : Yp0 + (size_t)(blk - SRCN) * BH;
    float acc[8] = {0,0,0,0,0,0,0,0};
    gemm8(acc, xin + (size_t)r0 * HN, W0 + h);
#pragma unroll
    for (int b = 0; b < 8; ++b) dst[(size_t)(r0 + b) * HN + h] = acc[b];
}

// ---------------------------------------------------------------------------
// step_kernel(s): three block classes in ONE dispatch
//   kind 0: layer-0 recurrence, diag t=s      (n0*4 blocks)
//   kind 1: proj1 (xp1/yp1 = HX0/HY0 @ W1), diag t=s-1 (np*4 blocks)
//   kind 2: layer-1 recurrence, diag t=s-2    (n1*4 blocks)
// Cross-step ordering / cross-XCD visibility via dispatch boundaries.
// ---------------------------------------------------------------------------
__global__ __launch_bounds__(256) void step_kernel(
    const float* __restrict__ W, const float* __restrict__ U,
    const float* __restrict__ bias, float* __restrict__ out,
    const float* __restrict__ xp0, const float* __restrict__ yp0, int s)
{
    const int n0 = (s <= 62) ? ncd(s) : 0;
    const int np = (s >= 1 && s <= 63) ? ncd(s - 1) : 0;
    int bid = blockIdx.x;
    int kind, t;
    if (bid < n0 * 4)             { kind = 0; t = s; }
    else if (bid < (n0 + np) * 4) { kind = 1; t = s - 1; bid -= n0 * 4; }
    else                          { kind = 2; t = s - 2; bid -= (n0 + np) * 4; }
    const int c = bid >> 2, tile = bid & 3;
    int i0 = t - 31; if (i0 < 0) i0 = 0;
    const int i = i0 + c, j = t - i;
    const size_t cOff = (size_t)(i * 32 + j) * CELL;

    const int tid = threadIdx.x;
    const int lane = tid & 63;
    const int bg = __builtin_amdgcn_readfirstlane(tid >> 6);
    const int h = tile * 64 + lane;
    const size_t r0H = (size_t)(bg * 8) * HN;

    if (kind == 1) {
        // proj1: out[1][cell].{HX,HY} = HX0[cell]@W1, HY0[cell]@W1
        const float* hx0 = out + cOff + r0H;
        const float* hy0 = hx0 + BH;
        const float* w1c = W + 65536 + h;
        float aX[8] = {0,0,0,0,0,0,0,0};
        float aY[8] = {0,0,0,0,0,0,0,0};
        gemm8(aX, hx0, w1c);
        gemm8(aY, hy0, w1c);
        float* xd = out + DSZ + cOff + r0H;
        float* yd = xd + BH;
#pragma unroll
        for (int b = 0; b < 8; ++b) {
            xd[b * HN + h] = aX[b];
            yd[b * HN + h] = aY[b];
        }
    } else {
        // recurrence: temp = sx@Ux + ph@Uy + bias; hx/hy = tanh(xp/yp + temp)
        const int d = (kind == 0) ? 0 : 1;
        const float* Ud = U + (size_t)d * 131072;
        float acc[8] = {0,0,0,0,0,0,0,0};
        if (i > 0) gemm8(acc, out + (size_t)d * DSZ + cOff - 32 * CELL + r0H, Ud + h);
        if (j > 0) gemm8(acc, out + (size_t)d * DSZ + cOff - CELL + r0H, Ud + 65536 + h);
        const float bv = bias[d * HN + h];
        float* oHX = out + (size_t)d * DSZ + cOff + r0H;
        float* oHY = oHX + BH;
        const float* xr;
        const float* yr;
        if (d == 0) { xr = xp0 + (size_t)i * BH + r0H; yr = yp0 + (size_t)j * BH + r0H; }
        else        { xr = oHX; yr = oHY; } // proj1 output, same-thread read->overwrite
#pragma unroll
        for (int b = 0; b < 8; ++b) {
            float tmp = acc[b] + bv;
            float xv = xr[b * HN + h];
            float yv = yr[b * HN + h];
            oHX[b * HN + h] = tanhf(xv + tmp);
            oHY[b * HN + h] = tanhf(yv + tmp);
        }
    }
}

// ===========================================================================
// Fallback (round-1 LDS ladder, proven): used only if ws_size is too small.
// ===========================================================================
__global__ __launch_bounds__(256) void proj0_kernel(
    const float* __restrict__ src, const float* __restrict__ trg,
    const float* __restrict__ W0, float* __restrict__ Xp0, float* __restrict__ Yp0)
{
    __shared__ float xs[BH];
    int blk = blockIdx.x >> 2, tile = blockIdx.x & 3;
    const float* X; float* P;
    if (blk < SRCN) { X = src + blk * BH; P = Xp0 + blk * BH; }
    else            { X = trg + (blk - SRCN) * BH; P = Yp0 + (blk - SRCN) * BH; }
    int tid = threadIdx.x;
    { const float4* x4 = (const float4*)X; float4* s4 = (float4*)xs;
#pragma unroll
      for (int r = 0; r < 8; ++r) s4[tid + r * 256] = x4[tid + r * 256]; }
    __syncthreads();
    int h = tile * 64 + (tid & 63), bg = tid >> 6;
    float acc[8] = {0,0,0,0,0,0,0,0};
    for (int k = 0; k < HN; k += 4) {
        float w0 = W0[(k+0)*HN+h], w1 = W0[(k+1)*HN+h], w2 = W0[(k+2)*HN+h], w3 = W0[(k+3)*HN+h];
#pragma unroll
        for (int bb = 0; bb < 8; ++bb) {
            int b = bg * 8 + bb;
            float4 xv = *(const float4*)&xs[b * HN + k];
            acc[bb] += xv.x*w0 + xv.y*w1 + xv.z*w2 + xv.w*w3;
        }
    }
#pragma unroll
    for (int bb = 0; bb < 8; ++bb) P[(bg*8+bb)*HN + h] = acc[bb];
}

__global__ __launch_bounds__(256) void proj1_kernel(
    float* __restrict__ out, const float* __restrict__ W1)
{
    __shared__ float hxs[BH];
    __shared__ float hys[BH];
    int cell = blockIdx.x >> 2, tile = blockIdx.x & 3;
    const float* hx0 = out + (size_t)cell * CELL;
    const float* hy0 = hx0 + BH;
    float* xp1 = out + DSZ + (size_t)cell * CELL;
    float* yp1 = xp1 + BH;
    int tid = threadIdx.x;
    { const float4* a4 = (const float4*)hx0; const float4* b4 = (const float4*)hy0;
      float4* sa = (float4*)hxs; float4* sb = (float4*)hys;
#pragma unroll
      for (int r = 0; r < 8; ++r) { sa[tid+r*256] = a4[tid+r*256]; sb[tid+r*256] = b4[tid+r*256]; } }
    __syncthreads();
    int h = tile * 64 + (tid & 63), bg = tid >> 6;
    float ax[8] = {0,0,0,0,0,0,0,0}, ay[8] = {0,0,0,0,0,0,0,0};
    for (int k = 0; k < HN; k += 4) {
        float w0 = W1[(k+0)*HN+h], w1 = W1[(k+1)*HN+h], w2 = W1[(k+2)*HN+h], w3 = W1[(k+3)*HN+h];
#pragma unroll
        for (int bb = 0; bb < 8; ++bb) {
            int b = bg * 8 + bb;
            float4 xv = *(const float4*)&hxs[b*HN+k];
            float4 yv = *(const float4*)&hys[b*HN+k];
            ax[bb] += xv.x*w0 + xv.y*w1 + xv.z*w2 + xv.w*w3;
            ay[bb] += yv.x*w0 + yv.y*w1 + yv.z*w2 + yv.w*w3;
        }
    }
#pragma unroll
    for (int bb = 0; bb < 8; ++bb) {
        int b = bg * 8 + bb;
        xp1[b*HN+h] = ax[bb]; yp1[b*HN+h] = ay[bb];
    }
}

__global__ __launch_bounds__(256) void diag_kernel(
    float* out, const float* __restrict__ U, const float* __restrict__ bias,
    const float* __restrict__ Xp0, const float* __restrict__ Yp0, int d, int t)
{
    __shared__ float sxs[BH];
    __shared__ float phs[BH];
    int c = blockIdx.x >> 2, tile = blockIdx.x & 3;
    int i0 = t - (TRGN - 1); if (i0 < 0) i0 = 0;
    int i = i0 + c, j = t - i;
    const float* Ux = U + d * (2 * HN * HN);
    const float* Uy = Ux + HN * HN;
    float* outD = out + (size_t)d * DSZ;
    const float* sx = (i > 0) ? outD + (size_t)((i-1)*TRGN + j) * CELL : nullptr;
    const float* ph = (j > 0) ? outD + (size_t)(i*TRGN + (j-1)) * CELL : nullptr;
    float* oHX = outD + (size_t)(i*TRGN + j) * CELL;
    float* oHY = oHX + BH;
    const float* xp = d ? oHX : (Xp0 + i * BH);
    const float* yp = d ? oHY : (Yp0 + j * BH);
    const float* bd = bias + d * HN;
    int tid = threadIdx.x;
    { const float4* s4 = (const float4*)sx; const float4* p4 = (const float4*)ph;
      float4* d1 = (float4*)sxs; float4* d2 = (float4*)phs;
      float4 z = make_float4(0.f,0.f,0.f,0.f);
#pragma unroll
      for (int r = 0; r < 8; ++r) { int idx = tid + r*256; d1[idx] = sx ? s4[idx] : z; d2[idx] = ph ? p4[idx] : z; } }
    __syncthreads();
    int h = tile * 64 + (tid & 63), bg = tid >> 6;
    float acc[8] = {0,0,0,0,0,0,0,0};
    for (int k = 0; k < HN; k += 4) {
        float ux0 = Ux[(k+0)*HN+h], ux1 = Ux[(k+1)*HN+h], ux2 = Ux[(k+2)*HN+h], ux3 = Ux[(k+3)*HN+h];
        float uy0 = Uy[(k+0)*HN+h], uy1 = Uy[(k+1)*HN+h], uy2 = Uy[(k+2)*HN+h], uy3 = Uy[(k+3)*HN+h];
#pragma unroll
        for (int bb = 0; bb < 8; ++bb) {
            int b = bg * 8 + bb;
            float4 sv = *(const float4*)&sxs[b*HN+k];
            float4 pv = *(const float4*)&phs[b*HN+k];
            acc[bb] += sv.x*ux0 + sv.y*ux1 + sv.z*ux2 + sv.w*ux3
                     + pv.x*uy0 + pv.y*uy1 + pv.z*uy2 + pv.w*uy3;
        }
    }
    float bv = bd[h];
#pragma unroll
    for (int bb = 0; bb < 8; ++bb) {
        int b = bg * 8 + bb;
        float temp = acc[bb] + bv;
        oHX[b*HN+h] = tanhf(xp[b*HN+h] + temp);
        oHY[b*HN+h] = tanhf(yp[b*HN+h] + temp);
    }
}

// ===========================================================================
extern "C" void kernel_launch(void* const* d_in, const int* in_sizes, int n_in,
                              void* d_out, int out_size, void* d_ws, size_t ws_size,
                              hipStream_t stream)
{
    const float* source = (const float*)d_in[0];
    const float* target = (const float*)d_in[1];
    const float* W      = (const float*)d_in[2]; // [2][256][256]
    const float* U      = (const float*)d_in[3]; // [2][512][256]
    const float* bias   = (const float*)d_in[4]; // [2][1][256]
    float* out = (float*)d_out;

    const size_t need = 2u * 1024 * 1024; // xp0 + yp0
    if (d_ws != nullptr && ws_size >= need) {
        float* xp0 = (float*)d_ws;
        float* yp0 = xp0 + 32 * BH;
        proj0s_kernel<<<dim3(64 * 4), dim3(256), 0, stream>>>(source, target, W, xp0, yp0);
        for (int s = 0; s < 65; ++s) {
            int n0 = (s <= 62) ? ncd(s) : 0;
            int np = (s >= 1 && s <= 63) ? ncd(s - 1) : 0;
            int n1 = (s >= 2) ? ncd(s - 2) : 0;
            step_kernel<<<dim3((n0 + np + n1) * 4), dim3(256), 0, stream>>>(
                W, U, bias, out, xp0, yp0, s);
        }
    } else {
        // Proven round-1 ladder (scratch aliased into out[1] region; safe
        // because proj1 runs only after ALL layer-0 diagonals).
        float* Xp0 = out + DSZ;
        float* Yp0 = Xp0 + SRCN * BH;
        proj0_kernel<<<dim3(64 * 4), dim3(256), 0, stream>>>(source, target, W, Xp0, Yp0);
        for (int t = 0; t < SRCN + TRGN - 1; ++t) {
            int nc = ncd(t);
            diag_kernel<<<dim3(nc * 4), dim3(256), 0, stream>>>(out, U, bias, Xp0, Yp0, 0, t);
        }
        proj1_kernel<<<dim3(1024 * 4), dim3(256), 0, stream>>>(out, W + HN * HN);
        for (int t = 0; t < SRCN + TRGN - 1; ++t) {
            int nc = ncd(t);
            diag_kernel<<<dim3(nc * 4), dim3(256), 0, stream>>>(out, U, bias, nullptr, nullptr, 1, t);
        }
    }
}

// Round 7
// 2887.195 us; speedup vs baseline: 1.2383x; 1.2383x over previous
//
#include <hip/hip_runtime.h>
#include <math.h>

// Grid-RNN (WhileOpGridLSTMNet): DEPTH=2, SRC=TRG=32, B=32, H=256
// out[d][i][j][c][b][h], c=0:HX, c=1:HY
#define SRCN 32
#define TRGN 32
#define BN   32
#define HN   256
#define BH   (BN*HN)          // 8192 floats per (cell,channel)
#define CELL (2*BH)           // 16384 floats per cell
#define DSZ  ((size_t)SRCN*TRGN*CELL) // floats per depth
#define LDST 260              // padded LDS row stride (floats), 16B-aligned

__host__ __device__ __forceinline__ int ncd(int t) { // cells on diag t (0..62)
    int a = t + 1, b = 63 - t;
    int m = a < b ? a : b;
    return m < 32 ? m : 32;
}

#define FMA8(ACC, S, A, B) \
    ACC[0] += (S) * (A).x; ACC[1] += (S) * (A).y; \
    ACC[2] += (S) * (A).z; ACC[3] += (S) * (A).w; \
    ACC[4] += (S) * (B).x; ACC[5] += (S) * (B).y; \
    ACC[6] += (S) * (B).z; ACC[7] += (S) * (B).w;

// ---------------------------------------------------------------------------
// proj0 (round-5 proven): xp0[i]=source[i]@W0 ; yp0[j]=target[j]@W0
// ---------------------------------------------------------------------------
__global__ __launch_bounds__(256) void proj0_kernel(
    const float* __restrict__ src, const float* __restrict__ trg,
    const float* __restrict__ W0, float* __restrict__ Xp0, float* __restrict__ Yp0)
{
    __shared__ float xs[BH];
    int blk = blockIdx.x >> 2, tile = blockIdx.x & 3;
    const float* X; float* P;
    if (blk < SRCN) { X = src + blk * BH; P = Xp0 + blk * BH; }
    else            { X = trg + (blk - SRCN) * BH; P = Yp0 + (blk - SRCN) * BH; }
    int tid = threadIdx.x;
    { const float4* x4 = (const float4*)X; float4* s4 = (float4*)xs;
#pragma unroll
      for (int r = 0; r < 8; ++r) s4[tid + r * 256] = x4[tid + r * 256]; }
    __syncthreads();
    int h = tile * 64 + (tid & 63), bg = tid >> 6;
    float acc[8] = {0,0,0,0,0,0,0,0};
    for (int k = 0; k < HN; k += 4) {
        float w0 = W0[(k+0)*HN+h], w1 = W0[(k+1)*HN+h], w2 = W0[(k+2)*HN+h], w3 = W0[(k+3)*HN+h];
#pragma unroll
        for (int bb = 0; bb < 8; ++bb) {
            int b = bg * 8 + bb;
            float4 xv = *(const float4*)&xs[b * HN + k];
            acc[bb] += xv.x*w0 + xv.y*w1 + xv.z*w2 + xv.w*w3;
        }
    }
#pragma unroll
    for (int bb = 0; bb < 8; ++bb) P[(bg*8+bb)*HN + h] = acc[bb];
}

// ---------------------------------------------------------------------------
// step_kernel(s): three block classes in ONE dispatch (schedule = round 5)
//   kind 0: layer-0 recurrence, diag t=s      (n0*4 blocks)
//   kind 1: proj1 (xp1/yp1 = HX0/HY0 @ W1), diag t=s-1 (np*4 blocks)
//   kind 2: layer-1 recurrence, diag t=s-2    (n1*4 blocks)
// Work layout: lane = (b-row, 8 h-cols). LDS reads are full-bandwidth
// per-lane-row ds_read_b128 (128/wave/stream), weights are 2-address
// broadcast loads from L1. Cross-step visibility via dispatch boundaries.
// ---------------------------------------------------------------------------
__global__ __launch_bounds__(256) void step_kernel(
    const float* __restrict__ W, const float* __restrict__ U,
    const float* __restrict__ bias, float* __restrict__ out,
    const float* __restrict__ xp0, const float* __restrict__ yp0, int s)
{
    __shared__ __align__(16) float sA[32 * LDST]; // 33280 B
    __shared__ __align__(16) float sB[32 * LDST]; // 33280 B
    const int n0 = (s <= 62) ? ncd(s) : 0;
    const int np = (s >= 1 && s <= 63) ? ncd(s - 1) : 0;
    int bid = blockIdx.x;
    int kind, t;
    if (bid < n0 * 4)             { kind = 0; t = s; }
    else if (bid < (n0 + np) * 4) { kind = 1; t = s - 1; bid -= n0 * 4; }
    else                          { kind = 2; t = s - 2; bid -= (n0 + np) * 4; }
    const int c = bid >> 2, tile = bid & 3;
    int i0 = t - 31; if (i0 < 0) i0 = 0;
    const int i = i0 + c, j = t - i;
    const size_t cOff = (size_t)(i * 32 + j) * CELL;
    const int tid = threadIdx.x;

    // ---- stage two 32x256 fp32 tiles into padded LDS ----
    const float *pa, *pb;
    if (kind == 0) {
        pa = (i > 0) ? out + cOff - 32 * CELL : nullptr;        // HX0[i-1,j]
        pb = (j > 0) ? out + cOff - CELL : nullptr;             // HX0[i,j-1]
    } else if (kind == 1) {
        pa = out + cOff;                                        // HX0[cell]
        pb = out + cOff + BH;                                   // HY0[cell]
    } else {
        pa = (i > 0) ? out + DSZ + cOff - 32 * CELL : nullptr;  // HX1[i-1,j]
        pb = (j > 0) ? out + DSZ + cOff - CELL : nullptr;       // HX1[i,j-1]
    }
    {
        const float4* a4 = (const float4*)pa;
        const float4* b4 = (const float4*)pb;
        const float4 z = make_float4(0.f, 0.f, 0.f, 0.f);
#pragma unroll
        for (int e = 0; e < 8; ++e) {
            int q   = tid + e * 256;       // f4 index 0..2047
            int row = q >> 6;              // 0..31
            int col = (q & 63) << 2;       // float col 0..252
            *(float4*)&sA[row * LDST + col] = pa ? a4[q] : z;
            *(float4*)&sB[row * LDST + col] = pb ? b4[q] : z;
        }
    }
    __syncthreads();

    const int lane = tid & 63, wv = tid >> 6;
    const int r  = lane & 31;                          // my b-row
    const int h0 = tile * 64 + wv * 16 + (lane >> 5) * 8; // my 8 h-cols
    const float* srA = &sA[r * LDST];
    const float* srB = &sB[r * LDST];

    if (kind == 1) {
        // ---- proj1: aX = HX0@W1, aY = HY0@W1 (shared weight loads) ----
        const float* w1 = W + 65536;
        float aX[8] = {0,0,0,0,0,0,0,0};
        float aY[8] = {0,0,0,0,0,0,0,0};
        for (int k = 0; k < 256; k += 4) {
            float4 sv = *(const float4*)&srA[k];
            float4 pv = *(const float4*)&srB[k];
            float sa[4] = {sv.x, sv.y, sv.z, sv.w};
            float pb4[4] = {pv.x, pv.y, pv.z, pv.w};
            const float* wr = w1 + (size_t)k * HN + h0;
#pragma unroll
            for (int q2 = 0; q2 < 4; ++q2) {
                float4 wa = *(const float4*)(wr + q2 * HN);
                float4 wb = *(const float4*)(wr + q2 * HN + 4);
                FMA8(aX, sa[q2], wa, wb);
                FMA8(aY, pb4[q2], wa, wb);
            }
        }
        float* xd = out + DSZ + cOff + (size_t)r * HN + h0;
        float* yd = xd + BH;
        *(float4*)&xd[0] = make_float4(aX[0], aX[1], aX[2], aX[3]);
        *(float4*)&xd[4] = make_float4(aX[4], aX[5], aX[6], aX[7]);
        *(float4*)&yd[0] = make_float4(aY[0], aY[1], aY[2], aY[3]);
        *(float4*)&yd[4] = make_float4(aY[4], aY[5], aY[6], aY[7]);
    } else {
        // ---- recurrence: temp = sx@Ux + ph@Uy + b; hx/hy = tanh(xp/yp+temp)
        const int d = (kind == 0) ? 0 : 1;
        const float* ux = U + (size_t)d * 131072;
        const float* uy = ux + 65536;
        float acc[8] = {0,0,0,0,0,0,0,0};
        for (int k = 0; k < 256; k += 4) {
            float4 sv = *(const float4*)&srA[k];
            float4 pv = *(const float4*)&srB[k];
            float sa[4] = {sv.x, sv.y, sv.z, sv.w};
            float pb4[4] = {pv.x, pv.y, pv.z, pv.w};
            const float* wx = ux + (size_t)k * HN + h0;
            const float* wy = uy + (size_t)k * HN + h0;
#pragma unroll
            for (int q2 = 0; q2 < 4; ++q2) {
                float4 xa = *(const float4*)(wx + q2 * HN);
                float4 xb = *(const float4*)(wx + q2 * HN + 4);
                float4 ya = *(const float4*)(wy + q2 * HN);
                float4 yb = *(const float4*)(wy + q2 * HN + 4);
                FMA8(acc, sa[q2], xa, xb);
                FMA8(acc, pb4[q2], ya, yb);
            }
        }
        float4 bv0 = *(const float4*)&bias[d * HN + h0];
        float4 bv1 = *(const float4*)&bias[d * HN + h0 + 4];
        float tb[8] = {bv0.x, bv0.y, bv0.z, bv0.w, bv1.x, bv1.y, bv1.z, bv1.w};
        float* oHX = out + (size_t)d * DSZ + cOff;
        float* oHY = oHX + BH;
        const float* xr;
        const float* yr;
        if (d == 0) { xr = xp0 + (size_t)i * BH; yr = yp0 + (size_t)j * BH; }
        else        { xr = oHX; yr = oHY; } // proj1 out: same-thread read->overwrite
        const float* xrr = xr + (size_t)r * HN + h0;
        const float* yrr = yr + (size_t)r * HN + h0;
        float4 xv0 = *(const float4*)&xrr[0], xv1 = *(const float4*)&xrr[4];
        float4 yv0 = *(const float4*)&yrr[0], yv1 = *(const float4*)&yrr[4];
        float xin[8] = {xv0.x, xv0.y, xv0.z, xv0.w, xv1.x, xv1.y, xv1.z, xv1.w};
        float yin[8] = {yv0.x, yv0.y, yv0.z, yv0.w, yv1.x, yv1.y, yv1.z, yv1.w};
        float hx[8], hy[8];
#pragma unroll
        for (int q2 = 0; q2 < 8; ++q2) {
            float tmp = acc[q2] + tb[q2];
            hx[q2] = tanhf(xin[q2] + tmp);
            hy[q2] = tanhf(yin[q2] + tmp);
        }
        float* ox = oHX + (size_t)r * HN + h0;
        float* oy = oHY + (size_t)r * HN + h0;
        *(float4*)&ox[0] = make_float4(hx[0], hx[1], hx[2], hx[3]);
        *(float4*)&ox[4] = make_float4(hx[4], hx[5], hx[6], hx[7]);
        *(float4*)&oy[0] = make_float4(hy[0], hy[1], hy[2], hy[3]);
        *(float4*)&oy[4] = make_float4(hy[4], hy[5], hy[6], hy[7]);
    }
}

// ===========================================================================
// Fallback (round-1 ladder, proven): used only if ws_size is too small.
// ===========================================================================
__global__ __launch_bounds__(256) void proj1_kernel(
    float* __restrict__ out, const float* __restrict__ W1)
{
    __shared__ float hxs[BH];
    __shared__ float hys[BH];
    int cell = blockIdx.x >> 2, tile = blockIdx.x & 3;
    const float* hx0 = out + (size_t)cell * CELL;
    const float* hy0 = hx0 + BH;
    float* xp1 = out + DSZ + (size_t)cell * CELL;
    float* yp1 = xp1 + BH;
    int tid = threadIdx.x;
    { const float4* a4 = (const float4*)hx0; const float4* b4 = (const float4*)hy0;
      float4* sa = (float4*)hxs; float4* sb = (float4*)hys;
#pragma unroll
      for (int r = 0; r < 8; ++r) { sa[tid+r*256] = a4[tid+r*256]; sb[tid+r*256] = b4[tid+r*256]; } }
    __syncthreads();
    int h = tile * 64 + (tid & 63), bg = tid >> 6;
    float ax[8] = {0,0,0,0,0,0,0,0}, ay[8] = {0,0,0,0,0,0,0,0};
    for (int k = 0; k < HN; k += 4) {
        float w0 = W1[(k+0)*HN+h], w1 = W1[(k+1)*HN+h], w2 = W1[(k+2)*HN+h], w3 = W1[(k+3)*HN+h];
#pragma unroll
        for (int bb = 0; bb < 8; ++bb) {
            int b = bg * 8 + bb;
            float4 xv = *(const float4*)&hxs[b*HN+k];
            float4 yv = *(const float4*)&hys[b*HN+k];
            ax[bb] += xv.x*w0 + xv.y*w1 + xv.z*w2 + xv.w*w3;
            ay[bb] += yv.x*w0 + yv.y*w1 + yv.z*w2 + yv.w*w3;
        }
    }
#pragma unroll
    for (int bb = 0; bb < 8; ++bb) {
        int b = bg * 8 + bb;
        xp1[b*HN+h] = ax[bb]; yp1[b*HN+h] = ay[bb];
    }
}

__global__ __launch_bounds__(256) void diag_kernel(
    float* out, const float* __restrict__ U, const float* __restrict__ bias,
    const float* __restrict__ Xp0, const float* __restrict__ Yp0, int d, int t)
{
    __shared__ float sxs[BH];
    __shared__ float phs[BH];
    int c = blockIdx.x >> 2, tile = blockIdx.x & 3;
    int i0 = t - (TRGN - 1); if (i0 < 0) i0 = 0;
    int i = i0 + c, j = t - i;
    const float* Ux = U + d * (2 * HN * HN);
    const float* Uy = Ux + HN * HN;
    float* outD = out + (size_t)d * DSZ;
    const float* sx = (i > 0) ? outD + (size_t)((i-1)*TRGN + j) * CELL : nullptr;
    const float* ph = (j > 0) ? outD + (size_t)(i*TRGN + (j-1)) * CELL : nullptr;
    float* oHX = outD + (size_t)(i*TRGN + j) * CELL;
    float* oHY = oHX + BH;
    const float* xp = d ? oHX : (Xp0 + i * BH);
    const float* yp = d ? oHY : (Yp0 + j * BH);
    const float* bd = bias + d * HN;
    int tid = threadIdx.x;
    { const float4* s4 = (const float4*)sx; const float4* p4 = (const float4*)ph;
      float4* d1 = (float4*)sxs; float4* d2 = (float4*)phs;
      float4 z = make_float4(0.f,0.f,0.f,0.f);
#pragma unroll
      for (int r = 0; r < 8; ++r) { int idx = tid + r*256; d1[idx] = sx ? s4[idx] : z; d2[idx] = ph ? p4[idx] : z; } }
    __syncthreads();
    int h = tile * 64 + (tid & 63), bg = tid >> 6;
    float acc[8] = {0,0,0,0,0,0,0,0};
    for (int k = 0; k < HN; k += 4) {
        float ux0 = Ux[(k+0)*HN+h], ux1 = Ux[(k+1)*HN+h], ux2 = Ux[(k+2)*HN+h], ux3 = Ux[(k+3)*HN+h];
        float uy0 = Uy[(k+0)*HN+h], uy1 = Uy[(k+1)*HN+h], uy2 = Uy[(k+2)*HN+h], uy3 = Uy[(k+3)*HN+h];
#pragma unroll
        for (int bb = 0; bb < 8; ++bb) {
            int b = bg * 8 + bb;
            float4 sv = *(const float4*)&sxs[b*HN+k];
            float4 pv = *(const float4*)&phs[b*HN+k];
            acc[bb] += sv.x*ux0 + sv.y*ux1 + sv.z*ux2 + sv.w*ux3
                     + pv.x*uy0 + pv.y*uy1 + pv.z*uy2 + pv.w*uy3;
        }
    }
    float bv = bd[h];
#pragma unroll
    for (int bb = 0; bb < 8; ++bb) {
        int b = bg * 8 + bb;
        float temp = acc[bb] + bv;
        oHX[b*HN+h] = tanhf(xp[b*HN+h] + temp);
        oHY[b*HN+h] = tanhf(yp[b*HN+h] + temp);
    }
}

// ===========================================================================
extern "C" void kernel_launch(void* const* d_in, const int* in_sizes, int n_in,
                              void* d_out, int out_size, void* d_ws, size_t ws_size,
                              hipStream_t stream)
{
    const float* source = (const float*)d_in[0];
    const float* target = (const float*)d_in[1];
    const float* W      = (const float*)d_in[2]; // [2][256][256]
    const float* U      = (const float*)d_in[3]; // [2][512][256]
    const float* bias   = (const float*)d_in[4]; // [2][1][256]
    float* out = (float*)d_out;

    const size_t need = 2u * 1024 * 1024; // xp0 + yp0
    if (d_ws != nullptr && ws_size >= need) {
        float* xp0 = (float*)d_ws;
        float* yp0 = xp0 + 32 * BH;
        proj0_kernel<<<dim3(64 * 4), dim3(256), 0, stream>>>(source, target, W, xp0, yp0);
        for (int s = 0; s < 65; ++s) {
            int n0 = (s <= 62) ? ncd(s) : 0;
            int np = (s >= 1 && s <= 63) ? ncd(s - 1) : 0;
            int n1 = (s >= 2) ? ncd(s - 2) : 0;
            step_kernel<<<dim3((n0 + np + n1) * 4), dim3(256), 0, stream>>>(
                W, U, bias, out, xp0, yp0, s);
        }
    } else {
        // Proven round-1 ladder (scratch aliased into out[1] region; safe
        // because proj1 runs only after ALL layer-0 diagonals).
        float* Xp0 = out + DSZ;
        float* Yp0 = Xp0 + SRCN * BH;
        proj0_kernel<<<dim3(64 * 4), dim3(256), 0, stream>>>(source, target, W, Xp0, Yp0);
        for (int t = 0; t < SRCN + TRGN - 1; ++t) {
            int nc = ncd(t);
            diag_kernel<<<dim3(nc * 4), dim3(256), 0, stream>>>(out, U, bias, Xp0, Yp0, 0, t);
        }
        proj1_kernel<<<dim3(1024 * 4), dim3(256), 0, stream>>>(out, W + HN * HN);
        for (int t = 0; t < SRCN + TRGN - 1; ++t) {
            int nc = ncd(t);
            diag_kernel<<<dim3(nc * 4), dim3(256), 0, stream>>>(out, U, bias, nullptr, nullptr, 1, t);
        }
    }
}